// Round 9
// baseline (252.255 us; speedup 1.0000x reference)
//
#include <hip/hip_runtime.h>

#define EPS 1e-5f

// Problem dims (fixed by setup_inputs)
constexpr int T  = 512;
constexpr int B  = 64;
constexpr int HU = 1024;
constexpr int S  = 1024;
constexpr int C  = B * HU;       // 65536 (b,hu) columns
constexpr int TCHUNK = 64;       // t rows per mega block
constexpr int NTC = T / TCHUNK;  // 8 part slabs
constexpr int KC  = 64;          // k per LDS tile (was 128; halves VGPR stg)
constexpr int NCH = HU / KC;     // 16 chunks
constexpr int LDR = KC + 1;      // 65 (odd): read banks (ln+k)%32 -> <=2-way

// ws layout (in floats); high-water ~2.3 MB
constexpr size_t OFF_SIW0 = 0;            // [64][10]
constexpr size_t OFF_W    = 1024;         // [512]   e^{s_tau}, tau<512
constexpr size_t OFF_ESC  = 2048;         // [32768] e^{s} for ALL (t,b) -> Z
constexpr size_t OFF_PART = 35840;        // [8][65536] partial weighted sums

// ---------------------------------------------------------------------------
// MLP head (10 -> 5 -> 1)
// ---------------------------------------------------------------------------
__device__ __forceinline__ float mlp_head(
    const float* __restrict__ u10,
    const float* __restrict__ b0, const float* __restrict__ g0,
    const float* __restrict__ be0,const float* __restrict__ m0,
    const float* __restrict__ v0,
    const float* __restrict__ W1, const float* __restrict__ b1,
    const float* __restrict__ g1, const float* __restrict__ be1,
    const float* __restrict__ m1, const float* __restrict__ v1,
    const float* __restrict__ W2, const float* __restrict__ b2) {
    float y[10];
#pragma unroll
    for (int j = 0; j < 10; ++j) {
        float u = (u10[j] + b0[j] - m0[j]) * (1.0f / sqrtf(v0[j] + EPS)) * g0[j]
                  + be0[j];
        y[j] = fmaxf(u, 0.f);
    }
    float z[5];
#pragma unroll
    for (int i = 0; i < 5; ++i) {
        float u = b1[i];
#pragma unroll
        for (int j = 0; j < 10; ++j) u = fmaf(y[j], W1[j * 5 + i], u);
        u = (u - m1[i]) * (1.0f / sqrtf(v1[i] + EPS)) * g1[i] + be1[i];
        z[i] = fmaxf(u, 0.f);
    }
    float sc = b2[0];
#pragma unroll
    for (int i = 0; i < 5; ++i) sc = fmaf(z[i], W2[i], sc);
    return sc;
}

// ---------------------------------------------------------------------------
// kA: the 512 USED weights w[tau] = e^{s(t,b)}, tau = t*64+b, t<8.
// Blocks with t==0 also export siW0[b][10]. (Proven r5/r7/r8 — unchanged.)
// ---------------------------------------------------------------------------
__global__ __launch_bounds__(256) void k_weights(
    const float* __restrict__ h,  const float* __restrict__ si,
    const float* __restrict__ W0,
    const float* __restrict__ b0, const float* __restrict__ g0,
    const float* __restrict__ be0,const float* __restrict__ m0,
    const float* __restrict__ v0,
    const float* __restrict__ W1, const float* __restrict__ b1,
    const float* __restrict__ g1, const float* __restrict__ be1,
    const float* __restrict__ m1, const float* __restrict__ v1,
    const float* __restrict__ W2, const float* __restrict__ b2,
    float* __restrict__ w, float* __restrict__ siW0out) {
    const int e   = blockIdx.x;
    const int t   = e >> 6;              // 0..7
    const int cb  = e & 63;              // b
    const int tid = threadIdx.x;
    const int wv  = tid >> 6, ln = tid & 63;

    const float4 hv = *(const float4*)(h  + (size_t)t  * C + (size_t)cb * HU + tid * 4);
    const float4 sv = *(const float4*)(si + (size_t)cb * S + tid * 4);
    const float* wsb = W0 + (size_t)(4 * tid) * 10;          // si half rows
    const float* whb = W0 + (size_t)(1024 + 4 * tid) * 10;   // h half rows

    float ssi[10], shh[10];
#pragma unroll
    for (int j = 0; j < 10; ++j) { ssi[j] = 0.f; shh[j] = 0.f; }
#pragma unroll
    for (int d = 0; d < 4; ++d) {
        const float sx = (&sv.x)[d], hx = (&hv.x)[d];
#pragma unroll
        for (int j = 0; j < 10; ++j) {
            ssi[j] = fmaf(sx, wsb[d * 10 + j], ssi[j]);
            shh[j] = fmaf(hx, whb[d * 10 + j], shh[j]);
        }
    }
#pragma unroll
    for (int j = 0; j < 10; ++j) {
#pragma unroll
        for (int off = 32; off > 0; off >>= 1) {
            ssi[j] += __shfl_down(ssi[j], off, 64);
            shh[j] += __shfl_down(shh[j], off, 64);
        }
    }
    __shared__ float rs[4][10], rh[4][10];
    if (ln == 0) {
#pragma unroll
        for (int j = 0; j < 10; ++j) { rs[wv][j] = ssi[j]; rh[wv][j] = shh[j]; }
    }
    __syncthreads();

    if (t == 0 && tid < 10)
        siW0out[cb * 10 + tid] = rs[0][tid] + rs[1][tid] + rs[2][tid] + rs[3][tid];

    if (tid == 0) {
        float u10[10];
#pragma unroll
        for (int j = 0; j < 10; ++j)
            u10[j] = rs[0][j] + rs[1][j] + rs[2][j] + rs[3][j] +
                     rh[0][j] + rh[1][j] + rh[2][j] + rh[3][j];
        const float sc = mlp_head(u10, b0, g0, be0, m0, v0,
                                  W1, b1, g1, be1, m1, v1, W2, b2);
        w[t * 64 + cb] = expf(sc);   // |sc| BN-bounded -> no max-sub needed
    }
}

// ---------------------------------------------------------------------------
// kB "mega" v3: ONE h pass for BOTH scores and weighted sums — occupancy-
// engineered: LDS 21.3 KB (park ALIASED into the tile buffer; tile reads all
// complete before the epilogue barrier) + __launch_bounds__(512,8) caps
// VGPR <= 64 -> 8 waves/SIMD -> 4 blocks/CU (32 waves/CU), 4 independent
// barrier groups per CU (was 2).
// KC=64: stg[8] regs; tile [64][65]. Bank analysis (all <=2-way = free):
//   staging writes (row+slane)%32; score reads (ln+klo+i)%32;
//   colsum reads (8*oct + kk + r)%32.
// Per chunk: barrier; stg->LDS; issue next chunk (T14); barrier;
//   scores: lane=t-row, wave k-slice 8 uniform k -> W0 scalar loads;
//   colsum: thread (kk=tid>>3, oct=tid&7): 8 rows, 3 shfl_xor, store part.
// Epilogue: park (aliased) + per-t-row head -> escore. h read ONCE.
// ---------------------------------------------------------------------------
__global__ __launch_bounds__(512, 8) void k_mega(
    const float* __restrict__ h,  const float* __restrict__ W0,
    const float* __restrict__ w,  const float* __restrict__ siW0,
    const float* __restrict__ b0, const float* __restrict__ g0,
    const float* __restrict__ be0,const float* __restrict__ m0,
    const float* __restrict__ v0,
    const float* __restrict__ W1, const float* __restrict__ b1,
    const float* __restrict__ g1, const float* __restrict__ be1,
    const float* __restrict__ m1, const float* __restrict__ v1,
    const float* __restrict__ W2, const float* __restrict__ b2,
    float* __restrict__ escore, float* __restrict__ part) {
    const int b   = blockIdx.x & 63;
    const int tc  = blockIdx.x >> 6;     // 0..7
    const int tid = threadIdx.x;
    const int wv  = tid >> 6;            // 0..7
    const int ln  = tid & 63;

    // buf: tile [64][65] = 4160 floats; epilogue park [8][64][10] = 5120
    // floats ALIASED into the same region (used only after final barrier).
    __shared__ float buf[5248];          // 21.0 KB
    __shared__ float wsl[64];            // this block's 64 weights

    if (tid < 64) wsl[tid] = w[tc * 64 + tid];

    const float* hb = h + (size_t)(tc * 64) * C + (size_t)b * HU;
    const int srow  = tid >> 5;          // 0..15 : rows 16q + srow
    const int slane = tid & 31;          // cols  32d + slane

    // prologue: chunk 0, 8 b32 per thread (coalesced 128B segments)
    float stg[8];
#pragma unroll
    for (int q = 0; q < 4; ++q)
#pragma unroll
        for (int d = 0; d < 2; ++d)
            stg[2 * q + d] = hb[(size_t)(16 * q + srow) * C + 32 * d + slane];

    const int klo = __builtin_amdgcn_readfirstlane(8 * wv);   // wave k-slice
    const int kk  = tid >> 3;            // colsum column 0..63
    const int oct = tid & 7;             // 8-row octile

    float sacc[10];
#pragma unroll
    for (int j = 0; j < 10; ++j) sacc[j] = 0.f;

    for (int c = 0; c < NCH; ++c) {
        if (c > 0) __syncthreads();      // prior chunk's readers done
        // conflict-free b32 writes: bank (row + slane)%32 -> <=2-way
#pragma unroll
        for (int q = 0; q < 4; ++q)
#pragma unroll
            for (int d = 0; d < 2; ++d)
                buf[(16 * q + srow) * LDR + 32 * d + slane] = stg[2 * q + d];
        if (c + 1 < NCH) {               // issue next chunk early (T14)
#pragma unroll
            for (int q = 0; q < 4; ++q)
#pragma unroll
                for (int d = 0; d < 2; ++d)
                    stg[2 * q + d] = hb[(size_t)(16 * q + srow) * C +
                                        (c + 1) * KC + 32 * d + slane];
        }
        __syncthreads();                 // tile ready

        // ---- scores: 8 uniform k's for this wave, lane = t-row ----
        const float* wp  = W0 + (size_t)(1024 + c * KC + klo) * 10;
        const float* shp = buf + ln * LDR + klo;
#pragma unroll
        for (int i = 0; i < 8; ++i) {
            const float hx = shp[i];     // bank (ln+klo+i)%32 -> 2/bank, free
#pragma unroll
            for (int j = 0; j < 10; ++j)
                sacc[j] = fmaf(hx, wp[i * 10 + j], sacc[j]);
        }

        // ---- colsum: part[tc][b][c*64+kk] = sum_t w[t]*tile[t][kk] ----
        float s = 0.f;
        const float* shc = buf + (8 * oct) * LDR + kk;
        const float* wl  = wsl + 8 * oct;
#pragma unroll
        for (int r = 0; r < 8; ++r)
            s = fmaf(wl[r], shc[r * LDR], s);   // bank (8oct+r+kk)%32, 2-way
        s += __shfl_xor(s, 1, 64);       // combine octiles
        s += __shfl_xor(s, 2, 64);
        s += __shfl_xor(s, 4, 64);
        if (oct == 0)
            part[(size_t)tc * C + (size_t)b * HU + c * KC + kk] = s;
    }

    // ---- epilogue: park (aliased into buf) + head per t-row ----
    __syncthreads();                     // all tile reads complete
#pragma unroll
    for (int j = 0; j < 10; ++j) buf[(wv * 64 + ln) * 10 + j] = sacc[j];
    __syncthreads();
    if (tid < 64) {
        float u10[10];
#pragma unroll
        for (int j = 0; j < 10; ++j) {
            float u = siW0[b * 10 + j];
#pragma unroll
            for (int wq = 0; wq < 8; ++wq) u += buf[(wq * 64 + tid) * 10 + j];
            u10[j] = u;
        }
        const float sc = mlp_head(u10, b0, g0, be0, m0, v0,
                                  W1, b1, g1, be1, m1, v1, W2, b2);
        escore[(size_t)(tc * 64 + tid) * 64 + b] = expf(sc);
    }
}

// ---------------------------------------------------------------------------
// kC: Z = sum(escore) (redundant per block, L2-hot), then
// out[c] = (1/Z) * sum_tc part[tc][c].  Grid 64 x 256 threads.
// ---------------------------------------------------------------------------
__global__ __launch_bounds__(256) void k_out(const float* __restrict__ part,
                                             const float* __restrict__ escore,
                                             float* __restrict__ out) {
    const int tid = threadIdx.x;
    const int wv  = tid >> 6, ln = tid & 63;

    float zs = 0.f;
#pragma unroll
    for (int q = 0; q < 32; ++q) {
        const float4 v = ((const float4*)escore)[tid + 256 * q];
        zs += v.x + v.y + v.z + v.w;
    }
#pragma unroll
    for (int off = 32; off > 0; off >>= 1)
        zs += __shfl_down(zs, off, 64);
    __shared__ float zr[4];
    __shared__ float sinv;
    if (ln == 0) zr[wv] = zs;
    __syncthreads();
    if (tid == 0) sinv = 1.0f / (zr[0] + zr[1] + zr[2] + zr[3]);
    __syncthreads();
    const float invZ = sinv;

    const int c = blockIdx.x * 1024 + tid * 4;
    float4 s = {0.f, 0.f, 0.f, 0.f};
#pragma unroll
    for (int ts = 0; ts < NTC; ++ts) {
        const float4 v = *(const float4*)(part + (size_t)ts * C + c);
        s.x += v.x; s.y += v.y; s.z += v.z; s.w += v.w;
    }
    s.x *= invZ; s.y *= invZ; s.z *= invZ; s.w *= invZ;
    *(float4*)(out + c) = s;
}

// ---------------------------------------------------------------------------
extern "C" void kernel_launch(void* const* d_in, const int* in_sizes, int n_in,
                              void* d_out, int out_size, void* d_ws, size_t ws_size,
                              hipStream_t stream) {
    const float* si  = (const float*)d_in[0];
    const float* h   = (const float*)d_in[1];
    const float* W0  = (const float*)d_in[2];
    const float* b0  = (const float*)d_in[3];
    const float* g0  = (const float*)d_in[4];
    const float* be0 = (const float*)d_in[5];
    const float* m0  = (const float*)d_in[6];
    const float* v0  = (const float*)d_in[7];
    const float* W1  = (const float*)d_in[8];
    const float* b1  = (const float*)d_in[9];
    const float* g1  = (const float*)d_in[10];
    const float* be1 = (const float*)d_in[11];
    const float* m1  = (const float*)d_in[12];
    const float* v1  = (const float*)d_in[13];
    const float* W2  = (const float*)d_in[14];
    const float* b2  = (const float*)d_in[15];

    float* ws     = (float*)d_ws;
    float* siW0   = ws + OFF_SIW0;
    float* w      = ws + OFF_W;
    float* escore = ws + OFF_ESC;
    float* part   = ws + OFF_PART;
    float* out    = (float*)d_out;

    hipLaunchKernelGGL(k_weights, dim3(512), dim3(256), 0, stream, h, si, W0,
                       b0, g0, be0, m0, v0, W1, b1, g1, be1, m1, v1, W2, b2,
                       w, siW0);
    hipLaunchKernelGGL(k_mega,    dim3(512), dim3(512), 0, stream, h, W0, w, siW0,
                       b0, g0, be0, m0, v0, W1, b1, g1, be1, m1, v1, W2, b2,
                       escore, part);
    hipLaunchKernelGGL(k_out,     dim3(64),  dim3(256), 0, stream, part, escore, out);
}